// Round 14
// baseline (37.122 us; speedup 1.0000x reference)
//
#include <hip/hip_runtime.h>

#define N_IMG 8
#define CIN   128
#define H_IN  56
#define W_IN  56
#define COUT  128
#define HW    3136
#define TROWS 9                        // tile rows [ro0-3, ro0+5], 2 output rows
#define TILE_B (TROWS * 56 * 256)      // 129024
#define PLA_OFF TILE_B                 // int4[1152]  = 18432 (corner addr bases + flags)
#define PLW_OFF (PLA_OFF + 18432)      // uint2[1152] = 9216  (4 x h16 weights)
#define PLC_OFF (PLW_OFF + 9216)       // int[1152]   = 4608  (global corner coords)
#define SMEM_TOTAL (PLC_OFF + 4608)    // 161280 <= 163840

typedef __attribute__((ext_vector_type(8))) short short8;
typedef __attribute__((ext_vector_type(4))) float f32x4;
typedef _Float16 h8 __attribute__((ext_vector_type(8)));

__device__ __forceinline__ unsigned short hb(float f) {
    _Float16 h = (_Float16)f;
    return __builtin_bit_cast(unsigned short, h);
}
__device__ __forceinline__ h8 splat8(unsigned short b) {
    _Float16 s = __builtin_bit_cast(_Float16, b);
    return (h8){s, s, s, s, s, s, s, s};
}
__device__ __forceinline__ void gload16(const void* g, void* l) {
    __builtin_amdgcn_global_load_lds(
        (const __attribute__((address_space(1))) unsigned int*)g,
        (__attribute__((address_space(3))) unsigned int*)l, 16, 0, 0);
}

// Issue 8 swizzled LDS gathers for one (tap,kc) unit; rare global fallback.
#define ISSUE(TAPV, CBS, PA0, PA1, G0,G1,G2,G3,H0,H1,H2,H3)                    \
  {                                                                            \
    G0 = *(const h8*)(smem + ((PA0.x & 0x7FFFFFFF) ^ (CBS)));                  \
    G1 = *(const h8*)(smem + ((PA0.y & 0x7FFFFFFF) ^ (CBS)));                  \
    G2 = *(const h8*)(smem + ((PA0.z & 0x7FFFFFFF) ^ (CBS)));                  \
    G3 = *(const h8*)(smem + ((PA0.w & 0x7FFFFFFF) ^ (CBS)));                  \
    H0 = *(const h8*)(smem + ((PA1.x & 0x7FFFFFFF) ^ (CBS)));                  \
    H1 = *(const h8*)(smem + ((PA1.y & 0x7FFFFFFF) ^ (CBS)));                  \
    H2 = *(const h8*)(smem + ((PA1.z & 0x7FFFFFFF) ^ (CBS)));                  \
    H3 = *(const h8*)(smem + ((PA1.w & 0x7FFFFFFF) ^ (CBS)));                  \
    bool qa0 = (unsigned)PA0.x >> 31, qa1 = (unsigned)PA0.y >> 31;             \
    bool qa2 = (unsigned)PA0.z >> 31, qa3 = (unsigned)PA0.w >> 31;             \
    bool qc0 = (unsigned)PA1.x >> 31, qc1 = (unsigned)PA1.y >> 31;             \
    bool qc2 = (unsigned)PA1.z >> 31, qc3 = (unsigned)PA1.w >> 31;             \
    if (__any(qa0 | qa1 | qa2 | qa3 | qc0 | qc1 | qc2 | qc3)) {                \
      int C0 = plC[eb0 + (TAPV) * 64], C1 = plC[eb1 + (TAPV) * 64];            \
      if (qa0) G0 = *(const h8*)(xim + (size_t)(int)((((C0 & 63) * 56 + ((C0 >> 12) & 63)) << 8) + (CBS))); \
      if (qa1) G1 = *(const h8*)(xim + (size_t)(int)((((C0 & 63) * 56 + ((C0 >> 18) & 63)) << 8) + (CBS))); \
      if (qa2) G2 = *(const h8*)(xim + (size_t)(int)(((((C0 >> 6) & 63) * 56 + ((C0 >> 12) & 63)) << 8) + (CBS))); \
      if (qa3) G3 = *(const h8*)(xim + (size_t)(int)(((((C0 >> 6) & 63) * 56 + ((C0 >> 18) & 63)) << 8) + (CBS))); \
      if (qc0) H0 = *(const h8*)(xim + (size_t)(int)((((C1 & 63) * 56 + ((C1 >> 12) & 63)) << 8) + (CBS))); \
      if (qc1) H1 = *(const h8*)(xim + (size_t)(int)((((C1 & 63) * 56 + ((C1 >> 18) & 63)) << 8) + (CBS))); \
      if (qc2) H2 = *(const h8*)(xim + (size_t)(int)(((((C1 >> 6) & 63) * 56 + ((C1 >> 12) & 63)) << 8) + (CBS))); \
      if (qc3) H3 = *(const h8*)(xim + (size_t)(int)(((((C1 >> 6) & 63) * 56 + ((C1 >> 18) & 63)) << 8) + (CBS))); \
    }                                                                          \
  }

// Interp both q-fragments + 16 MFMAs for one unit (B batch loaded first).
#define COMPUTE(G0,G1,G2,G3,H0,H1,H2,H3, PW0, PW1, BB)                         \
  {                                                                            \
    h8 b0 = *(const h8*)((BB));                                                \
    h8 b1 = *(const h8*)((BB) + 1024);                                         \
    h8 b2 = *(const h8*)((BB) + 2048);                                         \
    h8 b3 = *(const h8*)((BB) + 3072);                                         \
    h8 b4 = *(const h8*)((BB) + 4096);                                         \
    h8 b5 = *(const h8*)((BB) + 5120);                                         \
    h8 b6 = *(const h8*)((BB) + 6144);                                         \
    h8 b7 = *(const h8*)((BB) + 7168);                                         \
    h8 a0 = G0 * splat8((unsigned short)(PW0.x & 0xFFFF))                      \
          + G1 * splat8((unsigned short)(PW0.x >> 16))                         \
          + G2 * splat8((unsigned short)(PW0.y & 0xFFFF))                      \
          + G3 * splat8((unsigned short)(PW0.y >> 16));                        \
    h8 a1 = H0 * splat8((unsigned short)(PW1.x & 0xFFFF))                      \
          + H1 * splat8((unsigned short)(PW1.x >> 16))                         \
          + H2 * splat8((unsigned short)(PW1.y & 0xFFFF))                      \
          + H3 * splat8((unsigned short)(PW1.y >> 16));                        \
    acc[0][0] = __builtin_amdgcn_mfma_f32_16x16x32_f16(a0, b0, acc[0][0], 0, 0, 0); \
    acc[1][0] = __builtin_amdgcn_mfma_f32_16x16x32_f16(a1, b0, acc[1][0], 0, 0, 0); \
    acc[0][1] = __builtin_amdgcn_mfma_f32_16x16x32_f16(a0, b1, acc[0][1], 0, 0, 0); \
    acc[1][1] = __builtin_amdgcn_mfma_f32_16x16x32_f16(a1, b1, acc[1][1], 0, 0, 0); \
    acc[0][2] = __builtin_amdgcn_mfma_f32_16x16x32_f16(a0, b2, acc[0][2], 0, 0, 0); \
    acc[1][2] = __builtin_amdgcn_mfma_f32_16x16x32_f16(a1, b2, acc[1][2], 0, 0, 0); \
    acc[0][3] = __builtin_amdgcn_mfma_f32_16x16x32_f16(a0, b3, acc[0][3], 0, 0, 0); \
    acc[1][3] = __builtin_amdgcn_mfma_f32_16x16x32_f16(a1, b3, acc[1][3], 0, 0, 0); \
    acc[0][4] = __builtin_amdgcn_mfma_f32_16x16x32_f16(a0, b4, acc[0][4], 0, 0, 0); \
    acc[1][4] = __builtin_amdgcn_mfma_f32_16x16x32_f16(a1, b4, acc[1][4], 0, 0, 0); \
    acc[0][5] = __builtin_amdgcn_mfma_f32_16x16x32_f16(a0, b5, acc[0][5], 0, 0, 0); \
    acc[1][5] = __builtin_amdgcn_mfma_f32_16x16x32_f16(a1, b5, acc[1][5], 0, 0, 0); \
    acc[0][6] = __builtin_amdgcn_mfma_f32_16x16x32_f16(a0, b6, acc[0][6], 0, 0, 0); \
    acc[1][6] = __builtin_amdgcn_mfma_f32_16x16x32_f16(a1, b6, acc[1][6], 0, 0, 0); \
    acc[0][7] = __builtin_amdgcn_mfma_f32_16x16x32_f16(a0, b7, acc[0][7], 0, 0, 0); \
    acc[1][7] = __builtin_amdgcn_mfma_f32_16x16x32_f16(a1, b7, acc[1][7], 0, 0, 0); \
  }

// blocks 0..783: x (N,C,H,W) f32 -> xt (N,H,W,C) f16
// blocks 784..855: weight -> wr[tap][kc4][f][lane][8] f16 (B-fragment-linear)
__global__ __launch_bounds__(256) void prep_kernel(const float* __restrict__ x,
                                                   const float* __restrict__ w,
                                                   unsigned short* __restrict__ xt,
                                                   unsigned short* __restrict__ wr) {
    int b = blockIdx.x;
    int tid = threadIdx.x;
    if (b < 784) {
        int c = tid & 127;
        int half = tid >> 7;
        int n = b / 98;
        int hw0 = (b - n * 98) * 32 + half * 16;
        const float* xp = x + ((size_t)(n * CIN + c)) * HW + hw0;
        unsigned short* op = xt + ((size_t)n * HW + hw0) * CIN + c;
#pragma unroll
        for (int r = 0; r < 16; ++r) op[r * CIN] = hb(xp[r]);
    } else {
        int G = (b - 784) * 256 + tid;          // 0..18431 = 36*8*64
        int lane = G & 63;
        int f = (G >> 6) & 7;
        int kc4 = (G >> 9) & 3;
        int tap = G >> 11;
        int cout = f * 16 + (lane & 15);
        int ch = kc4 * 32 + (lane >> 4) * 8;
        short8 v;
#pragma unroll
        for (int j = 0; j < 8; ++j)
            v[j] = (short)hb(w[((size_t)cout * CIN + ch + j) * 9 + tap]);
        *(short8*)(wr + (size_t)G * 8) = v;
    }
}

__global__ __launch_bounds__(512, 2) void deform_main(
    const float* __restrict__ offset, const float* __restrict__ x2,
    const float* __restrict__ bias, const unsigned short* __restrict__ xt,
    const unsigned short* __restrict__ wr, float* __restrict__ out)
{
    extern __shared__ char smem[];
    int4*  plA = (int4*)(smem + PLA_OFF);
    uint2* plW = (uint2*)(smem + PLW_OFF);
    int*   plC = (int*)(smem + PLC_OFF);

    int tid = threadIdx.x;
    int orig = blockIdx.x;                 // 224 = 8 images * 28 row-pairs
    int n   = orig & 7;                    // one image per XCD
    int ro0 = (orig >> 3) * 2;             // first of 2 output rows

    const char* xim = (const char*)(xt + (size_t)n * HW * CIN);

    // ---- stage 9x56x128ch f16 tile, swizzled (slot = chunk ^ (p&15)) ----
#pragma unroll
    for (int s = 0; s < 16; ++s) {
        int d = s * 8192 + tid * 16;
        if (d < TILE_B) {
            int p = d >> 8;                // tile-linear pixel 0..503
            int tr = p / 56;
            int tx = p - tr * 56;
            int gy = min(max(ro0 - 3 + tr, 0), 55);
            int c  = ((d >> 4) & 15) ^ (p & 15);
            gload16(xim + (((gy * 56 + tx) << 8) + (c << 4)), smem + d);
        }
    }

    // ---- params: 1152 = 2 rows x 9 taps x 64 px ----
    for (int e = tid; e < 1152; e += 512) {
        int r = (e >= 576) ? 1 : 0;
        int e2 = e - r * 576;
        int tap = e2 >> 6;
        int px  = e2 & 63;
        int wo  = min(px, 55);
        int hor = ro0 + r;
        const float* offp = offset + ((size_t)n * 18 + tap * 2) * HW + hor * 56 + wo;
        float offy = offp[0];
        float offx = offp[HW];
        int ki = tap / 3;
        int kj = tap - ki * 3;
        float py  = (float)(hor - 1 + ki) + offy;
        float pxf = (float)(wo - 1 + kj) + offx;
        float y0f = floorf(py), x0f = floorf(pxf);
        float wy = py - y0f, wx = pxf - x0f;
        int y0 = (int)y0f, x0 = (int)x0f;
        int y1 = y0 + 1, x1 = x0 + 1;
        bool vy0 = (y0 >= 0) && (y0 < H_IN);
        bool vy1 = (y1 >= 0) && (y1 < H_IN);
        bool vx0 = (x0 >= 0) && (x0 < W_IN);
        bool vx1 = (x1 >= 0) && (x1 < W_IN);
        int cy0 = min(max(y0, 0), 55), cy1 = min(max(y1, 0), 55);
        int cx0 = min(max(x0, 0), 55), cx1 = min(max(x1, 0), 55);
        float w00 = (vy0 && vx0) ? (1.f - wy) * (1.f - wx) : 0.f;
        float w01 = (vy0 && vx1) ? (1.f - wy) * wx : 0.f;
        float w10 = (vy1 && vx0) ? wy * (1.f - wx) : 0.f;
        float w11 = (vy1 && vx1) ? wy * wx : 0.f;
        int f0 = (y0 < ro0 - 3 || y0 > ro0 + 5) ? 1 : 0;   // outside 9-row tile
        int f1 = (y1 < ro0 - 3 || y1 > ro0 + 5) ? 1 : 0;
        int tr0 = min(max(cy0 + 3 - ro0, 0), TROWS - 1);
        int tr1 = min(max(cy1 + 3 - ro0, 0), TROWS - 1);
        int p00 = tr0 * 56 + cx0, p01 = tr0 * 56 + cx1;
        int p10 = tr1 * 56 + cx0, p11 = tr1 * 56 + cx1;
        int4 A;
        A.x = ((p00 << 8) | ((p00 & 15) << 4)) | ((f0 && w00 != 0.f) ? 0x80000000 : 0);
        A.y = ((p01 << 8) | ((p01 & 15) << 4)) | ((f0 && w01 != 0.f) ? 0x80000000 : 0);
        A.z = ((p10 << 8) | ((p10 & 15) << 4)) | ((f1 && w10 != 0.f) ? 0x80000000 : 0);
        A.w = ((p11 << 8) | ((p11 & 15) << 4)) | ((f1 && w11 != 0.f) ? 0x80000000 : 0);
        plA[e] = A;
        uint2 W;
        W.x = (unsigned)hb(w00) | ((unsigned)hb(w01) << 16);
        W.y = (unsigned)hb(w10) | ((unsigned)hb(w11) << 16);
        plW[e] = W;
        plC[e] = cy0 | (cy1 << 6) | (cx0 << 12) | (cx1 << 18);
    }
    __syncthreads();   // tile + params visible; loop is barrier-free

    int lane = tid & 63;
    int w8 = tid >> 6;             // 8 waves = 2 kg x 4 mt
    int kg = w8 & 1;               // 64-channel half
    int mt = w8 >> 1;              // 32-px slot block (m=2)
    int llo = lane & 15, lhi = lane >> 4;
    int slot0 = mt * 32 + llo;     // px-frag 0
    int slot1 = slot0 + 16;        // px-frag 1
    int eb0 = (slot0 >> 6) * 576 + (slot0 & 63);
    int eb1 = (slot1 >> 6) * 576 + (slot1 & 63);
    const char* wrb = (const char*)wr;
    int cbs0 = ((kg * 2 + 0) * 4 + lhi) << 4;   // chunk byte offset, kc=0
    int cbs1 = ((kg * 2 + 1) * 4 + lhi) << 4;   // chunk byte offset, kc=1

    f32x4 acc[2][8] = {};

    int4  A0 = plA[eb0], A1 = plA[eb1];
    uint2 W0 = plW[eb0], W1 = plW[eb1];

    // software pipeline: gathers for unit u+1 in flight while unit u computes
    h8 xa0, xa1, xa2, xa3, ya0, ya1, ya2, ya3;   // set A
    h8 xb0, xb1, xb2, xb3, yb0, yb1, yb2, yb3;   // set B
    ISSUE(0, cbs0, A0, A1, xa0, xa1, xa2, xa3, ya0, ya1, ya2, ya3);

    for (int t = 0; t < 9; ++t) {
        int4 nA0, nA1; uint2 nW0, nW1;
        if (t < 8) {
            nA0 = plA[eb0 + (t + 1) * 64]; nA1 = plA[eb1 + (t + 1) * 64];
            nW0 = plW[eb0 + (t + 1) * 64]; nW1 = plW[eb1 + (t + 1) * 64];
        }
        // issue unit (t,1) gathers, then compute unit (t,0)
        ISSUE(t, cbs1, A0, A1, xb0, xb1, xb2, xb3, yb0, yb1, yb2, yb3);
        {
            const char* bb = wrb + (size_t)((t * 4 + kg * 2 + 0) * 8) * 1024 + lane * 16;
            COMPUTE(xa0, xa1, xa2, xa3, ya0, ya1, ya2, ya3, W0, W1, bb);
        }
        // issue unit (t+1,0) gathers, then compute unit (t,1)
        if (t < 8)
            ISSUE(t + 1, cbs0, nA0, nA1, xa0, xa1, xa2, xa3, ya0, ya1, ya2, ya3);
        {
            const char* bb = wrb + (size_t)((t * 4 + kg * 2 + 1) * 8) * 1024 + lane * 16;
            COMPUTE(xb0, xb1, xb2, xb3, yb0, yb1, yb2, yb3, W0, W1, bb);
        }
        if (t < 8) { A0 = nA0; A1 = nA1; W0 = nW0; W1 = nW1; }
    }

    // ---- split-K (kg=1 -> kg=0) via LDS (tile region reused), then epilogue ----
    __syncthreads();                       // all tile reads done WG-wide
    if (kg == 1) {
#pragma unroll
        for (int q = 0; q < 2; ++q)
#pragma unroll
            for (int f = 0; f < 8; ++f)
                *(f32x4*)(smem + ((((mt * 2 + q) * 8 + f) << 10) + (lane << 4))) = acc[q][f];
    }
    __syncthreads();
    if (kg == 0) {
#pragma unroll
        for (int q = 0; q < 2; ++q)
#pragma unroll
            for (int f = 0; f < 8; ++f) {
                size_t ro = (((mt * 2 + q) * 8 + f) << 10) + (lane << 4);
                acc[q][f] += *(const f32x4*)(smem + ro);
            }

#pragma unroll
        for (int q = 0; q < 2; ++q) {
            int slotq = mt * 32 + q * 16 + lhi * 4;   // 4 consecutive px slots
            int srow = slotq >> 6;
            int wo4 = slotq & 63;
            if (wo4 < 56) {
#pragma unroll
                for (int f = 0; f < 8; ++f) {
                    int cout = f * 16 + llo;
                    float bb = bias[cout];
                    size_t off = ((size_t)(n * COUT + cout)) * HW + (ro0 + srow) * 56 + wo4;
                    f32x4 xv = *(const f32x4*)(x2 + off);
                    f32x4 o;
#pragma unroll
                    for (int r = 0; r < 4; ++r) {
                        float v = acc[q][f][r] + bb + xv[r];
                        o[r] = v > 0.f ? v : 0.f;
                    }
                    *(f32x4*)(out + off) = o;
                }
            }
        }
    }
}

extern "C" void kernel_launch(void* const* d_in, const int* in_sizes, int n_in,
                              void* d_out, int out_size, void* d_ws, size_t ws_size,
                              hipStream_t stream) {
    const float* x      = (const float*)d_in[0];
    const float* offset = (const float*)d_in[1];
    const float* weight = (const float*)d_in[2];
    const float* bias   = (const float*)d_in[3];
    const float* x2     = (const float*)d_in[4];
    float* out = (float*)d_out;

    unsigned short* xt = (unsigned short*)d_ws;                       // 6,422,528 B
    unsigned short* wr = (unsigned short*)((char*)d_ws + 6422528ULL); // 294,912 B

    hipFuncSetAttribute((const void*)deform_main,
                        hipFuncAttributeMaxDynamicSharedMemorySize, SMEM_TOTAL);
    prep_kernel<<<856, 256, 0, stream>>>(x, weight, xt, wr);
    deform_main<<<224, 512, SMEM_TOTAL, stream>>>(offset, x2, bias, xt, wr, out);
}